// Round 7
// baseline (75.375 us; speedup 1.0000x reference)
//
#include <hip/hip_runtime.h>
#include <cstddef>
#include <stdint.h>

// Problem constants: B=8, Tx=Ty=E=D=256
#define NB 8
#define TX 256
#define TY 256
#define NE 256

// 2*log2(e): tanh(t) = 1 - 2*rcp(1+exp2(CSC*t)); the constant 1-term cancels in
// softmax, so score s = -2 * sum_e v[e]*rcp(1+exp2(ws'[e][x]+uh'[y][e]))
#define CSC 2.8853900817779268f

// ---------------- prep: WsT[b][e][x] and Uh[b][y][e], both pre-scaled by CSC ----
// Grid 256 x (64,8). blk<128 -> Ws (16 x-rows/block), else Uh (16 y-rows/block).
// Wave w computes rows {2w, 2w+1}; thread: 2 rows x 4 cols -> 8 FMA per M float4.
__global__ __launch_bounds__(512) void prep_kernel(
    const float* __restrict__ enc, const float* __restrict__ dec,
    const float* __restrict__ Wa, const float* __restrict__ Ua,
    float* __restrict__ WsT, float* __restrict__ Uh)
{
    const int tx = threadIdx.x;           // 0..63
    const int w  = threadIdx.y;           // 0..7
    const int tid = w * 64 + tx;
    int blk = blockIdx.x;
    const bool isU = blk >= 128;
    if (isU) blk -= 128;
    const int b  = blk >> 4;              // 0..7
    const int r0 = (blk & 15) * 16;       // 16 rows per block

    __shared__ float rowsL[16 * NE];      // 16 KB input rows
    __shared__ float tL[16][260];         // transpose buffer (Ws only)

    const float* src = (isU ? dec : enc) + ((size_t)b * 256 + r0) * NE;
    ((float4*)rowsL)[tid]       = ((const float4*)src)[tid];
    ((float4*)rowsL)[tid + 512] = ((const float4*)src)[tid + 512];
    __syncthreads();

    const float* M = isU ? Ua : Wa;
    const int e0 = tx * 4;
    const int rA = w * 2, rB = w * 2 + 1;
    float4 acc0 = make_float4(0.f, 0.f, 0.f, 0.f);
    float4 acc1 = make_float4(0.f, 0.f, 0.f, 0.f);
    const float* rowA = rowsL + rA * NE;
    const float* rowB = rowsL + rB * NE;

    for (int k = 0; k < NE; k += 8) {
        float4 mw[8];
        #pragma unroll
        for (int j = 0; j < 8; ++j)
            mw[j] = *(const float4*)(M + (size_t)(k + j) * NE + e0);
        #pragma unroll
        for (int j = 0; j < 8; ++j) {
            const float a = rowA[k + j];
            const float c = rowB[k + j];
            acc0.x = __builtin_fmaf(a, mw[j].x, acc0.x);
            acc0.y = __builtin_fmaf(a, mw[j].y, acc0.y);
            acc0.z = __builtin_fmaf(a, mw[j].z, acc0.z);
            acc0.w = __builtin_fmaf(a, mw[j].w, acc0.w);
            acc1.x = __builtin_fmaf(c, mw[j].x, acc1.x);
            acc1.y = __builtin_fmaf(c, mw[j].y, acc1.y);
            acc1.z = __builtin_fmaf(c, mw[j].z, acc1.z);
            acc1.w = __builtin_fmaf(c, mw[j].w, acc1.w);
        }
    }
    acc0.x *= CSC; acc0.y *= CSC; acc0.z *= CSC; acc0.w *= CSC;
    acc1.x *= CSC; acc1.y *= CSC; acc1.z *= CSC; acc1.w *= CSC;

    if (isU) {
        *(float4*)(Uh + ((size_t)b * TY + r0 + rA) * NE + e0) = acc0;
        *(float4*)(Uh + ((size_t)b * TY + r0 + rB) * NE + e0) = acc1;
    } else {
        *(float4*)&tL[rA][e0] = acc0;
        *(float4*)&tL[rB][e0] = acc1;
        __syncthreads();
        #pragma unroll
        for (int rep = 0; rep < 2; ++rep) {
            const int f4id = tid + rep * 512;
            const int e  = f4id >> 2;
            const int xq = (f4id & 3) * 4;
            float4 o;
            o.x = tL[xq + 0][e];
            o.y = tL[xq + 1][e];
            o.z = tL[xq + 2][e];
            o.w = tL[xq + 3][e];
            *(float4*)(WsT + (size_t)b * NE * TX + (size_t)e * TX + r0 + xq) = o;
        }
    }
}

// ---------------- attn: scores -> softmax -> context ----------------
// Grid 512 = (b, y-tile of 4). Block (64,8): wave w = (yl = w>>1, eh = w&1).
// Score: wave covers y=y0+yl, lane tx owns x-quad [4tx,4tx+4), e-half eh;
//   direct L2 b128 reads with 8-deep register prefetch, NO inner barriers.
// Softmax: combine 2 e-halves via LDS once, then wave-local shfl.
// Context: wave (yl, xh=eh): x-half, lane owns e-quad tx*4, 8-deep prefetch.
__global__ __launch_bounds__(512, 4) void attn_kernel(
    const float* __restrict__ enc, const float* __restrict__ WsT,
    const float* __restrict__ Uh, const float* __restrict__ Va,
    float* __restrict__ c_out, float* __restrict__ e_out)
{
    const int tx = threadIdx.x;            // 0..63
    const int w  = threadIdx.y;            // 0..7
    const int tid = w * 64 + tx;
    const int yl = w >> 1;                 // 0..3
    const int eh = w & 1;                  // 0..1 (e-half in score, x-half in ctx)
    const int b  = blockIdx.x >> 6;        // 0..7
    const int y0 = (blockIdx.x & 63) * 4;
    const int y  = y0 + yl;

    __shared__ float2 uvL[4][NE];          // 8 KB: (uh'[y][e], v[e])
    __shared__ float4 accL[2][4][64];      // 8 KB: partial combine (score & ctx)
    __shared__ float  pL[4][TX];           // 4 KB

    // stage (uh, v) pairs for the 4 y's
    #pragma unroll
    for (int i = tid; i < 4 * NE; i += 512) {
        const int yy = i >> 8;
        const int e  = i & 255;
        uvL[yy][e] = make_float2(Uh[((size_t)b * TY + y0 + yy) * NE + e], Va[e]);
    }
    __syncthreads();

    // ---- score: lane x-quad 4tx, e in [eh*128, eh*128+128), 8-deep prefetch ----
    const float* wp = WsT + (size_t)b * NE * TX + (size_t)(eh * 128) * TX + tx * 4;
    const float2* uvp = &uvL[yl][eh * 128];
    float4 acc = make_float4(0.f, 0.f, 0.f, 0.f);

    float4 buf[8];
    #pragma unroll
    for (int j = 0; j < 8; ++j) buf[j] = *(const float4*)(wp + (size_t)j * TX);

    for (int e0 = 0; e0 < 128; e0 += 8) {
        float4 cur[8];
        #pragma unroll
        for (int j = 0; j < 8; ++j) cur[j] = buf[j];
        if (e0 + 8 < 128) {
            #pragma unroll
            for (int j = 0; j < 8; ++j)
                buf[j] = *(const float4*)(wp + (size_t)(e0 + 8 + j) * TX);
        }
        #pragma unroll
        for (int j = 0; j < 8; ++j) {
            const float2 uv = uvp[e0 + j];
            const float r0 = __builtin_amdgcn_rcpf(1.f + __builtin_amdgcn_exp2f(cur[j].x + uv.x));
            const float r1 = __builtin_amdgcn_rcpf(1.f + __builtin_amdgcn_exp2f(cur[j].y + uv.x));
            const float r2 = __builtin_amdgcn_rcpf(1.f + __builtin_amdgcn_exp2f(cur[j].z + uv.x));
            const float r3 = __builtin_amdgcn_rcpf(1.f + __builtin_amdgcn_exp2f(cur[j].w + uv.x));
            acc.x = __builtin_fmaf(uv.y, r0, acc.x);
            acc.y = __builtin_fmaf(uv.y, r1, acc.y);
            acc.z = __builtin_fmaf(uv.y, r2, acc.z);
            acc.w = __builtin_fmaf(uv.y, r3, acc.w);
        }
    }
    accL[eh][yl][tx] = acc;
    __syncthreads();

    // ---- softmax over x (both eh waves compute; eh==0 stores) ----
    const float4 a0 = accL[0][yl][tx];
    const float4 a1 = accL[1][yl][tx];
    float4 s;
    s.x = -2.f * (a0.x + a1.x);
    s.y = -2.f * (a0.y + a1.y);
    s.z = -2.f * (a0.z + a1.z);
    s.w = -2.f * (a0.w + a1.w);

    float m = fmaxf(fmaxf(s.x, s.y), fmaxf(s.z, s.w));
    #pragma unroll
    for (int off = 32; off; off >>= 1) m = fmaxf(m, __shfl_xor(m, off));
    float4 p;
    p.x = __expf(s.x - m);
    p.y = __expf(s.y - m);
    p.z = __expf(s.z - m);
    p.w = __expf(s.w - m);
    float sum = (p.x + p.y) + (p.z + p.w);
    #pragma unroll
    for (int off = 32; off; off >>= 1) sum += __shfl_xor(sum, off);
    const float inv = __builtin_amdgcn_rcpf(sum);
    p.x *= inv; p.y *= inv; p.z *= inv; p.w *= inv;

    if (eh == 0) {
        *(float4*)(e_out + ((size_t)b * TY + y) * TX + tx * 4) = p;
        *(float4*)&pL[yl][tx * 4] = p;
    }
    __syncthreads();

    // ---- context: wave x-half xh=eh, lane e-quad tx*4, 8-deep prefetch ----
    const float* ep = enc + (size_t)b * TX * NE + (size_t)(eh * 128) * NE + tx * 4;
    const float* prow = &pL[yl][eh * 128];
    float4 cacc = make_float4(0.f, 0.f, 0.f, 0.f);

    float4 cbuf[8];
    #pragma unroll
    for (int j = 0; j < 8; ++j) cbuf[j] = *(const float4*)(ep + (size_t)j * NE);

    for (int x0 = 0; x0 < 128; x0 += 8) {
        float4 ccur[8];
        #pragma unroll
        for (int j = 0; j < 8; ++j) ccur[j] = cbuf[j];
        if (x0 + 8 < 128) {
            #pragma unroll
            for (int j = 0; j < 8; ++j)
                cbuf[j] = *(const float4*)(ep + (size_t)(x0 + 8 + j) * NE);
        }
        const float4 pa = *(const float4*)&prow[x0];
        const float4 pb = *(const float4*)&prow[x0 + 4];
        const float pv[8] = {pa.x, pa.y, pa.z, pa.w, pb.x, pb.y, pb.z, pb.w};
        #pragma unroll
        for (int j = 0; j < 8; ++j) {
            cacc.x = __builtin_fmaf(pv[j], ccur[j].x, cacc.x);
            cacc.y = __builtin_fmaf(pv[j], ccur[j].y, cacc.y);
            cacc.z = __builtin_fmaf(pv[j], ccur[j].z, cacc.z);
            cacc.w = __builtin_fmaf(pv[j], ccur[j].w, cacc.w);
        }
    }

    accL[eh][yl][tx] = cacc;
    __syncthreads();
    if (eh == 0) {
        const float4 c0 = accL[0][yl][tx];
        const float4 c1 = accL[1][yl][tx];
        float4 cs;
        cs.x = c0.x + c1.x;
        cs.y = c0.y + c1.y;
        cs.z = c0.z + c1.z;
        cs.w = c0.w + c1.w;
        *(float4*)(c_out + ((size_t)b * TY + y) * NE + tx * 4) = cs;
    }
}

extern "C" void kernel_launch(void* const* d_in, const int* in_sizes, int n_in,
                              void* d_out, int out_size, void* d_ws, size_t ws_size,
                              hipStream_t stream) {
    const float* enc = (const float*)d_in[0];   // [B,Tx,E]
    const float* dec = (const float*)d_in[1];   // [B,Ty,D]
    const float* Wa  = (const float*)d_in[2];   // [E,E]
    const float* Ua  = (const float*)d_in[3];   // [D,E]
    const float* Va  = (const float*)d_in[4];   // [E,1]

    float* c_out = (float*)d_out;                               // [B,Ty,E]
    float* e_out = (float*)d_out + (size_t)NB * TY * NE;        // [B,Ty,Tx]

    float* WsT = (float*)d_ws;                                  // [B][E][Tx]
    float* Uh  = (float*)d_ws + (size_t)NB * NE * TX;           // [B][Ty][E]

    prep_kernel<<<256, dim3(64, 8), 0, stream>>>(enc, dec, Wa, Ua, WsT, Uh);
    attn_kernel<<<512, dim3(64, 8), 0, stream>>>(enc, WsT, Uh, Va, c_out, e_out);
}

// Round 8
// 71.502 us; speedup vs baseline: 1.0542x; 1.0542x over previous
//
#include <hip/hip_runtime.h>
#include <cstddef>
#include <stdint.h>

// Problem constants: B=8, Tx=Ty=E=D=256
#define NB 8
#define TX 256
#define TY 256
#define NE 256

// 2*log2(e): tanh(t) = 1 - 2*rcp(1+exp2(CSC*t)).
// Score s = -2 * sum_e v[e] * rcp(1 + Zw[e][x]*Zu[y][e]),
// where Zw = exp2(CSC*Ws), Zu = exp2(CSC*Uh)  (exp2(a)*exp2(b) == exp2(a+b);
// the constant sum_e v term cancels in softmax).
#define CSC 2.8853900817779268f

// ---------------- prep: ZwT[b][e][x] = exp2(CSC*Ws), Zu[b][y][e] = exp2(CSC*Uh) ----
// Grid 512 x (64,8). blk<256 -> Ws (8 x-rows/block), else Uh (8 y-rows/block).
// Wave w computes row w; thread: 1 row x 4 cols.
__global__ __launch_bounds__(512) void prep_kernel(
    const float* __restrict__ enc, const float* __restrict__ dec,
    const float* __restrict__ Wa, const float* __restrict__ Ua,
    float* __restrict__ ZwT, float* __restrict__ Zu)
{
    const int tx = threadIdx.x;           // 0..63
    const int w  = threadIdx.y;           // 0..7
    const int tid = w * 64 + tx;
    int blk = blockIdx.x;
    const bool isU = blk >= 256;
    if (isU) blk -= 256;
    const int b  = blk >> 5;              // 0..7
    const int r0 = (blk & 31) * 8;        // 8 rows per block

    __shared__ float rowsL[8 * NE];       // 8 KB input rows
    __shared__ float tL[8][260];          // transpose buffer (Ws only)

    const float* src = (isU ? dec : enc) + ((size_t)b * 256 + r0) * NE;
    ((float4*)rowsL)[tid] = ((const float4*)src)[tid];   // 2048 floats
    __syncthreads();

    const float* M = isU ? Ua : Wa;
    const int e0 = tx * 4;
    float4 acc = make_float4(0.f, 0.f, 0.f, 0.f);
    const float* row = rowsL + w * NE;

    for (int k = 0; k < NE; k += 8) {
        float4 mw[8];
        #pragma unroll
        for (int j = 0; j < 8; ++j)
            mw[j] = *(const float4*)(M + (size_t)(k + j) * NE + e0);
        #pragma unroll
        for (int j = 0; j < 8; ++j) {
            const float a = row[k + j];
            acc.x = __builtin_fmaf(a, mw[j].x, acc.x);
            acc.y = __builtin_fmaf(a, mw[j].y, acc.y);
            acc.z = __builtin_fmaf(a, mw[j].z, acc.z);
            acc.w = __builtin_fmaf(a, mw[j].w, acc.w);
        }
    }
    // fused scale + exp2
    acc.x = __builtin_amdgcn_exp2f(acc.x * CSC);
    acc.y = __builtin_amdgcn_exp2f(acc.y * CSC);
    acc.z = __builtin_amdgcn_exp2f(acc.z * CSC);
    acc.w = __builtin_amdgcn_exp2f(acc.w * CSC);

    if (isU) {
        *(float4*)(Zu + ((size_t)b * TY + r0 + w) * NE + e0) = acc;
    } else {
        *(float4*)&tL[w][e0] = acc;
        __syncthreads();
        // transposed store: 512 float4s (256 e x 2 xq), 1 per thread
        const int e  = tid >> 1;
        const int xq = (tid & 1) * 4;
        float4 o;
        o.x = tL[xq + 0][e];
        o.y = tL[xq + 1][e];
        o.z = tL[xq + 2][e];
        o.w = tL[xq + 3][e];
        *(float4*)(ZwT + (size_t)b * NE * TX + (size_t)e * TX + r0 + xq) = o;
    }
}

// ---------------- attn: scores -> softmax -> context ----------------
// Grid 1024 = (b = blk&7 for XCD L2 affinity, y-pair = blk>>3). Block (64,8).
// Wave w = (yl = w>>2, eq = w&3): score partial for y=y0+yl over e-quarter eq;
// lane tx owns x-quad [4tx,4tx+4). Softmax: 4-partial LDS combine + wave shfl.
// Context: wave (yl, xq=eq): x-quarter, lane owns e-quad tx*4; 4-partial combine.
__global__ __launch_bounds__(512, 8) void attn_kernel(
    const float* __restrict__ enc, const float* __restrict__ ZwT,
    const float* __restrict__ Zu, const float* __restrict__ Va,
    float* __restrict__ c_out, float* __restrict__ e_out)
{
    const int tx = threadIdx.x;            // 0..63
    const int w  = threadIdx.y;            // 0..7
    const int tid = w * 64 + tx;
    const int yl = w >> 2;                 // 0..1
    const int eq = w & 3;                  // 0..3 (e-quarter in score, x-quarter in ctx)
    const int b  = blockIdx.x & 7;         // XCD-affine: all blocks of b on one XCD (if rr)
    const int y0 = (blockIdx.x >> 3) * 2;
    const int y  = y0 + yl;

    __shared__ float2 uvL[2][NE];          // 4 KB: (Zu[y][e], v[e])
    __shared__ float4 accL[4][2][64];      // 8 KB: partial combine (score & ctx)
    __shared__ float  pL[2][TX];           // 2 KB

    // stage (zu, v) pairs for the 2 y's: exactly 1 per thread
    {
        const int yy = tid >> 8;
        const int e  = tid & 255;
        uvL[yy][e] = make_float2(Zu[((size_t)b * TY + y0 + yy) * NE + e], Va[e]);
    }
    __syncthreads();

    // ---- score: lane x-quad 4tx, e in [eq*64, eq*64+64) ----
    const float* wp = ZwT + (size_t)b * NE * TX + (size_t)(eq * 64) * TX + tx * 4;
    const float2* uvp = &uvL[yl][eq * 64];
    float4 acc = make_float4(0.f, 0.f, 0.f, 0.f);
    #pragma unroll 8
    for (int e = 0; e < 64; ++e) {
        const float4 zw = *(const float4*)(wp + (size_t)e * TX);
        const float2 uv = uvp[e];
        const float r0 = __builtin_amdgcn_rcpf(__builtin_fmaf(zw.x, uv.x, 1.f));
        const float r1 = __builtin_amdgcn_rcpf(__builtin_fmaf(zw.y, uv.x, 1.f));
        const float r2 = __builtin_amdgcn_rcpf(__builtin_fmaf(zw.z, uv.x, 1.f));
        const float r3 = __builtin_amdgcn_rcpf(__builtin_fmaf(zw.w, uv.x, 1.f));
        acc.x = __builtin_fmaf(uv.y, r0, acc.x);
        acc.y = __builtin_fmaf(uv.y, r1, acc.y);
        acc.z = __builtin_fmaf(uv.y, r2, acc.z);
        acc.w = __builtin_fmaf(uv.y, r3, acc.w);
    }
    accL[eq][yl][tx] = acc;
    __syncthreads();

    // ---- softmax over x (all waves compute for their yl; eq==0 stores) ----
    const float4 a0 = accL[0][yl][tx];
    const float4 a1 = accL[1][yl][tx];
    const float4 a2 = accL[2][yl][tx];
    const float4 a3 = accL[3][yl][tx];
    float4 s;
    s.x = -2.f * ((a0.x + a1.x) + (a2.x + a3.x));
    s.y = -2.f * ((a0.y + a1.y) + (a2.y + a3.y));
    s.z = -2.f * ((a0.z + a1.z) + (a2.z + a3.z));
    s.w = -2.f * ((a0.w + a1.w) + (a2.w + a3.w));

    float m = fmaxf(fmaxf(s.x, s.y), fmaxf(s.z, s.w));
    #pragma unroll
    for (int off = 32; off; off >>= 1) m = fmaxf(m, __shfl_xor(m, off));
    float4 p;
    p.x = __expf(s.x - m);
    p.y = __expf(s.y - m);
    p.z = __expf(s.z - m);
    p.w = __expf(s.w - m);
    float sum = (p.x + p.y) + (p.z + p.w);
    #pragma unroll
    for (int off = 32; off; off >>= 1) sum += __shfl_xor(sum, off);
    const float inv = __builtin_amdgcn_rcpf(sum);
    p.x *= inv; p.y *= inv; p.z *= inv; p.w *= inv;

    if (eq == 0) {
        *(float4*)(e_out + ((size_t)b * TY + y) * TX + tx * 4) = p;
        *(float4*)&pL[yl][tx * 4] = p;
    }
    __syncthreads();

    // ---- context: wave x-quarter xq=eq, lane e-quad tx*4 ----
    const float* ep = enc + (size_t)b * TX * NE + (size_t)(eq * 64) * NE + tx * 4;
    const float* prow = &pL[yl][eq * 64];
    float4 cacc = make_float4(0.f, 0.f, 0.f, 0.f);
    #pragma unroll 8
    for (int x = 0; x < 64; ++x) {
        const float4 ev = *(const float4*)(ep + (size_t)x * NE);
        const float pv = prow[x];
        cacc.x = __builtin_fmaf(pv, ev.x, cacc.x);
        cacc.y = __builtin_fmaf(pv, ev.y, cacc.y);
        cacc.z = __builtin_fmaf(pv, ev.z, cacc.z);
        cacc.w = __builtin_fmaf(pv, ev.w, cacc.w);
    }
    accL[eq][yl][tx] = cacc;
    __syncthreads();
    if (eq == 0) {
        const float4 c0 = accL[0][yl][tx];
        const float4 c1 = accL[1][yl][tx];
        const float4 c2 = accL[2][yl][tx];
        const float4 c3 = accL[3][yl][tx];
        float4 cs;
        cs.x = (c0.x + c1.x) + (c2.x + c3.x);
        cs.y = (c0.y + c1.y) + (c2.y + c3.y);
        cs.z = (c0.z + c1.z) + (c2.z + c3.z);
        cs.w = (c0.w + c1.w) + (c2.w + c3.w);
        *(float4*)(c_out + ((size_t)b * TY + y) * NE + tx * 4) = cs;
    }
}

extern "C" void kernel_launch(void* const* d_in, const int* in_sizes, int n_in,
                              void* d_out, int out_size, void* d_ws, size_t ws_size,
                              hipStream_t stream) {
    const float* enc = (const float*)d_in[0];   // [B,Tx,E]
    const float* dec = (const float*)d_in[1];   // [B,Ty,D]
    const float* Wa  = (const float*)d_in[2];   // [E,E]
    const float* Ua  = (const float*)d_in[3];   // [D,E]
    const float* Va  = (const float*)d_in[4];   // [E,1]

    float* c_out = (float*)d_out;                               // [B,Ty,E]
    float* e_out = (float*)d_out + (size_t)NB * TY * NE;        // [B,Ty,Tx]

    float* ZwT = (float*)d_ws;                                  // [B][E][Tx]
    float* Zu  = (float*)d_ws + (size_t)NB * NE * TX;           // [B][Ty][E]

    prep_kernel<<<512, dim3(64, 8), 0, stream>>>(enc, dec, Wa, Ua, ZwT, Zu);
    attn_kernel<<<1024, dim3(64, 8), 0, stream>>>(enc, ZwT, Zu, Va, c_out, e_out);
}

// Round 9
// 43.008 us; speedup vs baseline: 1.7526x; 1.6625x over previous
//
#include <hip/hip_runtime.h>
#include <cstddef>
#include <stdint.h>

// Problem constants: B=8, Tx=Ty=E=D=256
#define NB 8
#define TX 256
#define TY 256
#define NE 256

// 2*log2(e): tanh(t) = 1 - 2*rcp(1+exp2(CSC*t)).
// Score s = -2 * sum_e v[e] * rcp(1 + Zw[e][x]*Zu[y][e]),
// Zw = exp2(CSC*Ws), Zu = exp2(CSC*Uh); constant sum_e v cancels in softmax.
#define CSC 2.8853900817779268f

// ---------------- prep: ZwT[b][e][x] = exp2(CSC*Ws), Zu[b][y][e] = exp2(CSC*Uh) ----
// Grid 256 x (64,8). blk<128 -> Ws (16 x-rows/block), else Uh (16 y-rows/block).
// Wave w computes rows {2w,2w+1}; thread: 2 rows x 4 cols -> 8 FMA per M float4.
__global__ __launch_bounds__(512) void prep_kernel(
    const float* __restrict__ enc, const float* __restrict__ dec,
    const float* __restrict__ Wa, const float* __restrict__ Ua,
    float* __restrict__ ZwT, float* __restrict__ Zu)
{
    const int tx = threadIdx.x;           // 0..63
    const int w  = threadIdx.y;           // 0..7
    const int tid = w * 64 + tx;
    int blk = blockIdx.x;
    const bool isU = blk >= 128;
    if (isU) blk -= 128;
    const int b  = blk >> 4;              // 0..7
    const int r0 = (blk & 15) * 16;       // 16 rows per block

    __shared__ float rowsL[16 * NE];      // 16 KB input rows
    __shared__ float tL[16][260];         // transpose buffer (Ws only)

    const float* src = (isU ? dec : enc) + ((size_t)b * 256 + r0) * NE;
    ((float4*)rowsL)[tid]       = ((const float4*)src)[tid];
    ((float4*)rowsL)[tid + 512] = ((const float4*)src)[tid + 512];
    __syncthreads();

    const float* M = isU ? Ua : Wa;
    const int e0 = tx * 4;
    const int rA = w * 2, rB = w * 2 + 1;
    float4 acc0 = make_float4(0.f, 0.f, 0.f, 0.f);
    float4 acc1 = make_float4(0.f, 0.f, 0.f, 0.f);
    const float* rowA = rowsL + rA * NE;
    const float* rowB = rowsL + rB * NE;

    for (int k = 0; k < NE; k += 8) {
        float4 mw[8];
        #pragma unroll
        for (int j = 0; j < 8; ++j)
            mw[j] = *(const float4*)(M + (size_t)(k + j) * NE + e0);
        #pragma unroll
        for (int j = 0; j < 8; ++j) {
            const float a = rowA[k + j];
            const float c = rowB[k + j];
            acc0.x = __builtin_fmaf(a, mw[j].x, acc0.x);
            acc0.y = __builtin_fmaf(a, mw[j].y, acc0.y);
            acc0.z = __builtin_fmaf(a, mw[j].z, acc0.z);
            acc0.w = __builtin_fmaf(a, mw[j].w, acc0.w);
            acc1.x = __builtin_fmaf(c, mw[j].x, acc1.x);
            acc1.y = __builtin_fmaf(c, mw[j].y, acc1.y);
            acc1.z = __builtin_fmaf(c, mw[j].z, acc1.z);
            acc1.w = __builtin_fmaf(c, mw[j].w, acc1.w);
        }
    }
    // fused scale + exp2
    acc0.x = __builtin_amdgcn_exp2f(acc0.x * CSC);
    acc0.y = __builtin_amdgcn_exp2f(acc0.y * CSC);
    acc0.z = __builtin_amdgcn_exp2f(acc0.z * CSC);
    acc0.w = __builtin_amdgcn_exp2f(acc0.w * CSC);
    acc1.x = __builtin_amdgcn_exp2f(acc1.x * CSC);
    acc1.y = __builtin_amdgcn_exp2f(acc1.y * CSC);
    acc1.z = __builtin_amdgcn_exp2f(acc1.z * CSC);
    acc1.w = __builtin_amdgcn_exp2f(acc1.w * CSC);

    if (isU) {
        *(float4*)(Zu + ((size_t)b * TY + r0 + rA) * NE + e0) = acc0;
        *(float4*)(Zu + ((size_t)b * TY + r0 + rB) * NE + e0) = acc1;
    } else {
        *(float4*)&tL[rA][e0] = acc0;
        *(float4*)&tL[rB][e0] = acc1;
        __syncthreads();
        // transposed store: 1024 float4s (256 e x 4 xq), 2 per thread
        #pragma unroll
        for (int rep = 0; rep < 2; ++rep) {
            const int f4id = tid + rep * 512;
            const int e  = f4id >> 2;
            const int xq = (f4id & 3) * 4;
            float4 o;
            o.x = tL[xq + 0][e];
            o.y = tL[xq + 1][e];
            o.z = tL[xq + 2][e];
            o.w = tL[xq + 3][e];
            *(float4*)(ZwT + (size_t)b * NE * TX + (size_t)e * TX + r0 + xq) = o;
        }
    }
}

// ---------------- attn: scores -> softmax -> context ----------------
// Grid 512 = (b = blk&7 XCD-affine, y-tile of 4 = blk>>3). Block (64,8).
// Score: wave w owns e-eighth [32w,32w+32); lane tx owns x-quad [4tx,4tx+4);
//   each zw load amortized over ALL 4 y's (zu4 = one LDS b128).
// Softmax: 8-partial LDS combine; wave w handles y=w&3 (2x duplicated); w<4 stores.
// Context: wave w owns x-eighth [32w,32w+32); lane owns e-quad 4tx; all 4 y's.
__global__ __launch_bounds__(512, 4) void attn_kernel(
    const float* __restrict__ enc, const float* __restrict__ ZwT,
    const float* __restrict__ Zu, const float* __restrict__ Va,
    float* __restrict__ c_out, float* __restrict__ e_out)
{
    const int tx = threadIdx.x;            // 0..63
    const int w  = threadIdx.y;            // 0..7
    const int tid = w * 64 + tx;
    const int b  = blockIdx.x & 7;         // XCD-affine if rr dispatch
    const int y0 = (blockIdx.x >> 3) * 4;

    __shared__ float4 zu4L[NE];            // 4 KB: {Zu[y0..y0+3][e]}
    __shared__ float  vL[NE];              // 1 KB
    __shared__ float4 accL[8][4][64];      // 32 KB: per-wave partials (score & ctx)
    __shared__ float  pL4[TX][4];          // 4 KB: p[x][y-local]

    // stage zu4 (threads 0..255) and v (threads 256..511)
    {
        const int e = tid & 255;
        if (tid < 256) {
            const float* zp = Zu + ((size_t)b * TY + y0) * NE + e;
            zu4L[e] = make_float4(zp[0], zp[NE], zp[2 * NE], zp[3 * NE]);
        } else {
            vL[e] = Va[e];
        }
    }
    __syncthreads();

    // ---- score: wave e-range [32w, 32w+32), lane x-quad 4tx, 4 y's per load ----
    const float* wp = ZwT + (size_t)b * NE * TX + (size_t)(w * 32) * TX + tx * 4;
    const float4* zup = &zu4L[w * 32];
    const float*  vp  = &vL[w * 32];
    float4 acc0 = make_float4(0.f, 0.f, 0.f, 0.f);
    float4 acc1 = acc0, acc2 = acc0, acc3 = acc0;
    #pragma unroll 4
    for (int e = 0; e < 32; ++e) {
        const float4 zw  = *(const float4*)(wp + (size_t)e * TX);
        const float4 zu4 = zup[e];
        const float  v   = vp[e];
        // y = 0
        acc0.x = __builtin_fmaf(v, __builtin_amdgcn_rcpf(__builtin_fmaf(zw.x, zu4.x, 1.f)), acc0.x);
        acc0.y = __builtin_fmaf(v, __builtin_amdgcn_rcpf(__builtin_fmaf(zw.y, zu4.x, 1.f)), acc0.y);
        acc0.z = __builtin_fmaf(v, __builtin_amdgcn_rcpf(__builtin_fmaf(zw.z, zu4.x, 1.f)), acc0.z);
        acc0.w = __builtin_fmaf(v, __builtin_amdgcn_rcpf(__builtin_fmaf(zw.w, zu4.x, 1.f)), acc0.w);
        // y = 1
        acc1.x = __builtin_fmaf(v, __builtin_amdgcn_rcpf(__builtin_fmaf(zw.x, zu4.y, 1.f)), acc1.x);
        acc1.y = __builtin_fmaf(v, __builtin_amdgcn_rcpf(__builtin_fmaf(zw.y, zu4.y, 1.f)), acc1.y);
        acc1.z = __builtin_fmaf(v, __builtin_amdgcn_rcpf(__builtin_fmaf(zw.z, zu4.y, 1.f)), acc1.z);
        acc1.w = __builtin_fmaf(v, __builtin_amdgcn_rcpf(__builtin_fmaf(zw.w, zu4.y, 1.f)), acc1.w);
        // y = 2
        acc2.x = __builtin_fmaf(v, __builtin_amdgcn_rcpf(__builtin_fmaf(zw.x, zu4.z, 1.f)), acc2.x);
        acc2.y = __builtin_fmaf(v, __builtin_amdgcn_rcpf(__builtin_fmaf(zw.y, zu4.z, 1.f)), acc2.y);
        acc2.z = __builtin_fmaf(v, __builtin_amdgcn_rcpf(__builtin_fmaf(zw.z, zu4.z, 1.f)), acc2.z);
        acc2.w = __builtin_fmaf(v, __builtin_amdgcn_rcpf(__builtin_fmaf(zw.w, zu4.z, 1.f)), acc2.w);
        // y = 3
        acc3.x = __builtin_fmaf(v, __builtin_amdgcn_rcpf(__builtin_fmaf(zw.x, zu4.w, 1.f)), acc3.x);
        acc3.y = __builtin_fmaf(v, __builtin_amdgcn_rcpf(__builtin_fmaf(zw.y, zu4.w, 1.f)), acc3.y);
        acc3.z = __builtin_fmaf(v, __builtin_amdgcn_rcpf(__builtin_fmaf(zw.z, zu4.w, 1.f)), acc3.z);
        acc3.w = __builtin_fmaf(v, __builtin_amdgcn_rcpf(__builtin_fmaf(zw.w, zu4.w, 1.f)), acc3.w);
    }
    accL[w][0][tx] = acc0;
    accL[w][1][tx] = acc1;
    accL[w][2][tx] = acc2;
    accL[w][3][tx] = acc3;
    __syncthreads();

    // ---- softmax: wave w handles y-local = w&3 (waves 4..7 duplicate) ----
    const int yy = w & 3;
    float4 s = make_float4(0.f, 0.f, 0.f, 0.f);
    #pragma unroll
    for (int ww = 0; ww < 8; ++ww) {
        const float4 a = accL[ww][yy][tx];
        s.x += a.x; s.y += a.y; s.z += a.z; s.w += a.w;
    }
    s.x *= -2.f; s.y *= -2.f; s.z *= -2.f; s.w *= -2.f;

    float m = fmaxf(fmaxf(s.x, s.y), fmaxf(s.z, s.w));
    #pragma unroll
    for (int off = 32; off; off >>= 1) m = fmaxf(m, __shfl_xor(m, off));
    float4 p;
    p.x = __expf(s.x - m);
    p.y = __expf(s.y - m);
    p.z = __expf(s.z - m);
    p.w = __expf(s.w - m);
    float sum = (p.x + p.y) + (p.z + p.w);
    #pragma unroll
    for (int off = 32; off; off >>= 1) sum += __shfl_xor(sum, off);
    const float inv = __builtin_amdgcn_rcpf(sum);
    p.x *= inv; p.y *= inv; p.z *= inv; p.w *= inv;

    if (w < 4) {
        *(float4*)(e_out + ((size_t)b * TY + y0 + yy) * TX + tx * 4) = p;
        pL4[tx * 4 + 0][yy] = p.x;
        pL4[tx * 4 + 1][yy] = p.y;
        pL4[tx * 4 + 2][yy] = p.z;
        pL4[tx * 4 + 3][yy] = p.w;
    }
    __syncthreads();

    // ---- context: wave x-range [32w, 32w+32), lane e-quad 4tx, 4 y's per load ----
    const float* ep = enc + (size_t)b * TX * NE + (size_t)(w * 32) * NE + tx * 4;
    float4 c0 = make_float4(0.f, 0.f, 0.f, 0.f);
    float4 c1 = c0, c2 = c0, c3 = c0;
    #pragma unroll 4
    for (int x = 0; x < 32; ++x) {
        const float4 ev = *(const float4*)(ep + (size_t)x * NE);
        const float4 p4 = *(const float4*)&pL4[w * 32 + x][0];
        c0.x = __builtin_fmaf(p4.x, ev.x, c0.x);
        c0.y = __builtin_fmaf(p4.x, ev.y, c0.y);
        c0.z = __builtin_fmaf(p4.x, ev.z, c0.z);
        c0.w = __builtin_fmaf(p4.x, ev.w, c0.w);
        c1.x = __builtin_fmaf(p4.y, ev.x, c1.x);
        c1.y = __builtin_fmaf(p4.y, ev.y, c1.y);
        c1.z = __builtin_fmaf(p4.y, ev.z, c1.z);
        c1.w = __builtin_fmaf(p4.y, ev.w, c1.w);
        c2.x = __builtin_fmaf(p4.z, ev.x, c2.x);
        c2.y = __builtin_fmaf(p4.z, ev.y, c2.y);
        c2.z = __builtin_fmaf(p4.z, ev.z, c2.z);
        c2.w = __builtin_fmaf(p4.z, ev.w, c2.w);
        c3.x = __builtin_fmaf(p4.w, ev.x, c3.x);
        c3.y = __builtin_fmaf(p4.w, ev.y, c3.y);
        c3.z = __builtin_fmaf(p4.w, ev.z, c3.z);
        c3.w = __builtin_fmaf(p4.w, ev.w, c3.w);
    }
    __syncthreads();   // accL reads (softmax) done; safe to overwrite
    accL[w][0][tx] = c0;
    accL[w][1][tx] = c1;
    accL[w][2][tx] = c2;
    accL[w][3][tx] = c3;
    __syncthreads();

    if (w < 4) {
        float4 cs = make_float4(0.f, 0.f, 0.f, 0.f);
        #pragma unroll
        for (int ww = 0; ww < 8; ++ww) {
            const float4 t = accL[ww][w][tx];
            cs.x += t.x; cs.y += t.y; cs.z += t.z; cs.w += t.w;
        }
        *(float4*)(c_out + ((size_t)b * TY + y0 + w) * NE + tx * 4) = cs;
    }
}

extern "C" void kernel_launch(void* const* d_in, const int* in_sizes, int n_in,
                              void* d_out, int out_size, void* d_ws, size_t ws_size,
                              hipStream_t stream) {
    const float* enc = (const float*)d_in[0];   // [B,Tx,E]
    const float* dec = (const float*)d_in[1];   // [B,Ty,D]
    const float* Wa  = (const float*)d_in[2];   // [E,E]
    const float* Ua  = (const float*)d_in[3];   // [D,E]
    const float* Va  = (const float*)d_in[4];   // [E,1]

    float* c_out = (float*)d_out;                               // [B,Ty,E]
    float* e_out = (float*)d_out + (size_t)NB * TY * NE;        // [B,Ty,Tx]

    float* ZwT = (float*)d_ws;                                  // [B][E][Tx]
    float* Zu  = (float*)d_ws + (size_t)NB * NE * TX;           // [B][Ty][E]

    prep_kernel<<<256, dim3(64, 8), 0, stream>>>(enc, dec, Wa, Ua, ZwT, Zu);
    attn_kernel<<<512, dim3(64, 8), 0, stream>>>(enc, ZwT, Zu, Va, c_out, e_out);
}

// Round 10
// 39.614 us; speedup vs baseline: 1.9027x; 1.0857x over previous
//
#include <hip/hip_runtime.h>
#include <cstddef>
#include <stdint.h>

// Problem constants: B=8, Tx=Ty=E=D=256
#define NB 8
#define TX 256
#define TY 256
#define NE 256

// 2*log2(e): tanh(t) = 1 - 2*rcp(1+exp2(CSC*t)).
// Score s = -2 * sum_e v[e] * rcp(1 + Zw[e][x]*Zu[y][e]),
// Zw = exp2(CSC*Ws), Zu = exp2(CSC*Uh); constant sum_e v cancels in softmax.
#define CSC 2.8853900817779268f

__device__ __forceinline__ void gload_lds16(const float* g, float* l) {
    __builtin_amdgcn_global_load_lds(
        (const __attribute__((address_space(1))) void*)g,
        (__attribute__((address_space(3))) void*)l,
        16, 0, 0);
}

// ---------------- prep: ZwT[b][e][x] = exp2(CSC*Ws), Zu[b][y][e] = exp2(CSC*Uh) ----
// Grid 256 x (64,8). blk<128 -> Ws (16 x-rows/block), else Uh (16 y-rows/block).
// M (Wa or Ua) is staged through LDS in 16-row chunks (16 KB, double-buffered),
// shared by all 8 waves -> M L2 traffic 8x lower than per-wave streaming.
// Wave w computes rows {2w,2w+1}; lane owns col-quad 4tx; 8 FMA per LDS b128.
__global__ __launch_bounds__(512) void prep_kernel(
    const float* __restrict__ enc, const float* __restrict__ dec,
    const float* __restrict__ Wa, const float* __restrict__ Ua,
    float* __restrict__ ZwT, float* __restrict__ Zu)
{
    const int tx = threadIdx.x;           // 0..63
    const int w  = threadIdx.y;           // 0..7
    const int tid = w * 64 + tx;
    int blk = blockIdx.x;
    const bool isU = blk >= 128;
    if (isU) blk -= 128;
    const int b  = blk >> 4;              // 0..7
    const int r0 = (blk & 15) * 16;       // 16 rows per block

    __shared__ float rowsL[16 * NE];      // 16 KB input rows
    __shared__ float MbL[2][16 * NE];     // 32 KB M chunk double-buffer
    __shared__ float tL[16][260];         // 16.6 KB transpose buffer (Ws only)

    const float* M = isU ? Ua : Wa;

    // stage M chunk 0 (async) + input rows (plain), one barrier
    gload_lds16(M + tid * 4,        MbL[0] + w * 256);
    gload_lds16(M + 2048 + tid * 4, MbL[0] + 2048 + w * 256);
    const float* src = (isU ? dec : enc) + ((size_t)b * 256 + r0) * NE;
    ((float4*)rowsL)[tid]       = ((const float4*)src)[tid];
    ((float4*)rowsL)[tid + 512] = ((const float4*)src)[tid + 512];
    __syncthreads();

    const int e0 = tx * 4;
    const int rA = w * 2, rB = w * 2 + 1;
    float4 acc0 = make_float4(0.f, 0.f, 0.f, 0.f);
    float4 acc1 = make_float4(0.f, 0.f, 0.f, 0.f);
    const float* rowA = rowsL + rA * NE;
    const float* rowB = rowsL + rB * NE;

    for (int c = 0; c < 16; ++c) {
        if (c < 15) {   // issue next chunk early; drained by the end-of-iter barrier
            const float* g = M + (size_t)(c + 1) * 4096;
            float* dst = MbL[(c + 1) & 1];
            gload_lds16(g + tid * 4,        dst + w * 256);
            gload_lds16(g + 2048 + tid * 4, dst + 2048 + w * 256);
        }
        const float* mb = MbL[c & 1] + e0;
        const int kbase = c * 16;
        #pragma unroll
        for (int j = 0; j < 16; ++j) {
            const float4 mw = *(const float4*)(mb + j * NE);
            const float a = rowA[kbase + j];
            const float d = rowB[kbase + j];
            acc0.x = __builtin_fmaf(a, mw.x, acc0.x);
            acc0.y = __builtin_fmaf(a, mw.y, acc0.y);
            acc0.z = __builtin_fmaf(a, mw.z, acc0.z);
            acc0.w = __builtin_fmaf(a, mw.w, acc0.w);
            acc1.x = __builtin_fmaf(d, mw.x, acc1.x);
            acc1.y = __builtin_fmaf(d, mw.y, acc1.y);
            acc1.z = __builtin_fmaf(d, mw.z, acc1.z);
            acc1.w = __builtin_fmaf(d, mw.w, acc1.w);
        }
        __syncthreads();   // drains own vmcnt -> chunk c+1 landed for all waves
    }

    // fused scale + exp2
    acc0.x = __builtin_amdgcn_exp2f(acc0.x * CSC);
    acc0.y = __builtin_amdgcn_exp2f(acc0.y * CSC);
    acc0.z = __builtin_amdgcn_exp2f(acc0.z * CSC);
    acc0.w = __builtin_amdgcn_exp2f(acc0.w * CSC);
    acc1.x = __builtin_amdgcn_exp2f(acc1.x * CSC);
    acc1.y = __builtin_amdgcn_exp2f(acc1.y * CSC);
    acc1.z = __builtin_amdgcn_exp2f(acc1.z * CSC);
    acc1.w = __builtin_amdgcn_exp2f(acc1.w * CSC);

    if (isU) {
        *(float4*)(Zu + ((size_t)b * TY + r0 + rA) * NE + e0) = acc0;
        *(float4*)(Zu + ((size_t)b * TY + r0 + rB) * NE + e0) = acc1;
    } else {
        *(float4*)&tL[rA][e0] = acc0;
        *(float4*)&tL[rB][e0] = acc1;
        __syncthreads();
        // transposed store: 1024 float4s (256 e x 4 xq), 2 per thread
        #pragma unroll
        for (int rep = 0; rep < 2; ++rep) {
            const int f4id = tid + rep * 512;
            const int e  = f4id >> 2;
            const int xq = (f4id & 3) * 4;
            float4 o;
            o.x = tL[xq + 0][e];
            o.y = tL[xq + 1][e];
            o.z = tL[xq + 2][e];
            o.w = tL[xq + 3][e];
            *(float4*)(ZwT + (size_t)b * NE * TX + (size_t)e * TX + r0 + xq) = o;
        }
    }
}

// ---------------- attn: scores -> softmax -> context (unchanged from round 9) ----
__global__ __launch_bounds__(512, 4) void attn_kernel(
    const float* __restrict__ enc, const float* __restrict__ ZwT,
    const float* __restrict__ Zu, const float* __restrict__ Va,
    float* __restrict__ c_out, float* __restrict__ e_out)
{
    const int tx = threadIdx.x;            // 0..63
    const int w  = threadIdx.y;            // 0..7
    const int tid = w * 64 + tx;
    const int b  = blockIdx.x & 7;         // XCD-affine if rr dispatch
    const int y0 = (blockIdx.x >> 3) * 4;

    __shared__ float4 zu4L[NE];            // 4 KB: {Zu[y0..y0+3][e]}
    __shared__ float  vL[NE];              // 1 KB
    __shared__ float4 accL[8][4][64];      // 32 KB: per-wave partials (score & ctx)
    __shared__ float  pL4[TX][4];          // 4 KB: p[x][y-local]

    {
        const int e = tid & 255;
        if (tid < 256) {
            const float* zp = Zu + ((size_t)b * TY + y0) * NE + e;
            zu4L[e] = make_float4(zp[0], zp[NE], zp[2 * NE], zp[3 * NE]);
        } else {
            vL[e] = Va[e];
        }
    }
    __syncthreads();

    // ---- score: wave e-range [32w, 32w+32), lane x-quad 4tx, 4 y's per load ----
    const float* wp = ZwT + (size_t)b * NE * TX + (size_t)(w * 32) * TX + tx * 4;
    const float4* zup = &zu4L[w * 32];
    const float*  vp  = &vL[w * 32];
    float4 acc0 = make_float4(0.f, 0.f, 0.f, 0.f);
    float4 acc1 = acc0, acc2 = acc0, acc3 = acc0;
    #pragma unroll 4
    for (int e = 0; e < 32; ++e) {
        const float4 zw  = *(const float4*)(wp + (size_t)e * TX);
        const float4 zu4 = zup[e];
        const float  v   = vp[e];
        acc0.x = __builtin_fmaf(v, __builtin_amdgcn_rcpf(__builtin_fmaf(zw.x, zu4.x, 1.f)), acc0.x);
        acc0.y = __builtin_fmaf(v, __builtin_amdgcn_rcpf(__builtin_fmaf(zw.y, zu4.x, 1.f)), acc0.y);
        acc0.z = __builtin_fmaf(v, __builtin_amdgcn_rcpf(__builtin_fmaf(zw.z, zu4.x, 1.f)), acc0.z);
        acc0.w = __builtin_fmaf(v, __builtin_amdgcn_rcpf(__builtin_fmaf(zw.w, zu4.x, 1.f)), acc0.w);
        acc1.x = __builtin_fmaf(v, __builtin_amdgcn_rcpf(__builtin_fmaf(zw.x, zu4.y, 1.f)), acc1.x);
        acc1.y = __builtin_fmaf(v, __builtin_amdgcn_rcpf(__builtin_fmaf(zw.y, zu4.y, 1.f)), acc1.y);
        acc1.z = __builtin_fmaf(v, __builtin_amdgcn_rcpf(__builtin_fmaf(zw.z, zu4.y, 1.f)), acc1.z);
        acc1.w = __builtin_fmaf(v, __builtin_amdgcn_rcpf(__builtin_fmaf(zw.w, zu4.y, 1.f)), acc1.w);
        acc2.x = __builtin_fmaf(v, __builtin_amdgcn_rcpf(__builtin_fmaf(zw.x, zu4.z, 1.f)), acc2.x);
        acc2.y = __builtin_fmaf(v, __builtin_amdgcn_rcpf(__builtin_fmaf(zw.y, zu4.z, 1.f)), acc2.y);
        acc2.z = __builtin_fmaf(v, __builtin_amdgcn_rcpf(__builtin_fmaf(zw.z, zu4.z, 1.f)), acc2.z);
        acc2.w = __builtin_fmaf(v, __builtin_amdgcn_rcpf(__builtin_fmaf(zw.w, zu4.z, 1.f)), acc2.w);
        acc3.x = __builtin_fmaf(v, __builtin_amdgcn_rcpf(__builtin_fmaf(zw.x, zu4.w, 1.f)), acc3.x);
        acc3.y = __builtin_fmaf(v, __builtin_amdgcn_rcpf(__builtin_fmaf(zw.y, zu4.w, 1.f)), acc3.y);
        acc3.z = __builtin_fmaf(v, __builtin_amdgcn_rcpf(__builtin_fmaf(zw.z, zu4.w, 1.f)), acc3.z);
        acc3.w = __builtin_fmaf(v, __builtin_amdgcn_rcpf(__builtin_fmaf(zw.w, zu4.w, 1.f)), acc3.w);
    }
    accL[w][0][tx] = acc0;
    accL[w][1][tx] = acc1;
    accL[w][2][tx] = acc2;
    accL[w][3][tx] = acc3;
    __syncthreads();

    // ---- softmax: wave w handles y-local = w&3 (waves 4..7 duplicate) ----
    const int yy = w & 3;
    float4 s = make_float4(0.f, 0.f, 0.f, 0.f);
    #pragma unroll
    for (int ww = 0; ww < 8; ++ww) {
        const float4 a = accL[ww][yy][tx];
        s.x += a.x; s.y += a.y; s.z += a.z; s.w += a.w;
    }
    s.x *= -2.f; s.y *= -2.f; s.z *= -2.f; s.w *= -2.f;

    float m = fmaxf(fmaxf(s.x, s.y), fmaxf(s.z, s.w));
    #pragma unroll
    for (int off = 32; off; off >>= 1) m = fmaxf(m, __shfl_xor(m, off));
    float4 p;
    p.x = __expf(s.x - m);
    p.y = __expf(s.y - m);
    p.z = __expf(s.z - m);
    p.w = __expf(s.w - m);
    float sum = (p.x + p.y) + (p.z + p.w);
    #pragma unroll
    for (int off = 32; off; off >>= 1) sum += __shfl_xor(sum, off);
    const float inv = __builtin_amdgcn_rcpf(sum);
    p.x *= inv; p.y *= inv; p.z *= inv; p.w *= inv;

    if (w < 4) {
        *(float4*)(e_out + ((size_t)b * TY + y0 + yy) * TX + tx * 4) = p;
        pL4[tx * 4 + 0][yy] = p.x;
        pL4[tx * 4 + 1][yy] = p.y;
        pL4[tx * 4 + 2][yy] = p.z;
        pL4[tx * 4 + 3][yy] = p.w;
    }
    __syncthreads();

    // ---- context: wave x-range [32w, 32w+32), lane e-quad 4tx, 4 y's per load ----
    const float* ep = enc + (size_t)b * TX * NE + (size_t)(w * 32) * NE + tx * 4;
    float4 c0 = make_float4(0.f, 0.f, 0.f, 0.f);
    float4 c1 = c0, c2 = c0, c3 = c0;
    #pragma unroll 4
    for (int x = 0; x < 32; ++x) {
        const float4 ev = *(const float4*)(ep + (size_t)x * NE);
        const float4 p4 = *(const float4*)&pL4[w * 32 + x][0];
        c0.x = __builtin_fmaf(p4.x, ev.x, c0.x);
        c0.y = __builtin_fmaf(p4.x, ev.y, c0.y);
        c0.z = __builtin_fmaf(p4.x, ev.z, c0.z);
        c0.w = __builtin_fmaf(p4.x, ev.w, c0.w);
        c1.x = __builtin_fmaf(p4.y, ev.x, c1.x);
        c1.y = __builtin_fmaf(p4.y, ev.y, c1.y);
        c1.z = __builtin_fmaf(p4.y, ev.z, c1.z);
        c1.w = __builtin_fmaf(p4.y, ev.w, c1.w);
        c2.x = __builtin_fmaf(p4.z, ev.x, c2.x);
        c2.y = __builtin_fmaf(p4.z, ev.y, c2.y);
        c2.z = __builtin_fmaf(p4.z, ev.z, c2.z);
        c2.w = __builtin_fmaf(p4.z, ev.w, c2.w);
        c3.x = __builtin_fmaf(p4.w, ev.x, c3.x);
        c3.y = __builtin_fmaf(p4.w, ev.y, c3.y);
        c3.z = __builtin_fmaf(p4.w, ev.z, c3.z);
        c3.w = __builtin_fmaf(p4.w, ev.w, c3.w);
    }
    __syncthreads();   // accL reads (softmax) done; safe to overwrite
    accL[w][0][tx] = c0;
    accL[w][1][tx] = c1;
    accL[w][2][tx] = c2;
    accL[w][3][tx] = c3;
    __syncthreads();

    if (w < 4) {
        float4 cs = make_float4(0.f, 0.f, 0.f, 0.f);
        #pragma unroll
        for (int ww = 0; ww < 8; ++ww) {
            const float4 t = accL[ww][w][tx];
            cs.x += t.x; cs.y += t.y; cs.z += t.z; cs.w += t.w;
        }
        *(float4*)(c_out + ((size_t)b * TY + y0 + w) * NE + tx * 4) = cs;
    }
}

extern "C" void kernel_launch(void* const* d_in, const int* in_sizes, int n_in,
                              void* d_out, int out_size, void* d_ws, size_t ws_size,
                              hipStream_t stream) {
    const float* enc = (const float*)d_in[0];   // [B,Tx,E]
    const float* dec = (const float*)d_in[1];   // [B,Ty,D]
    const float* Wa  = (const float*)d_in[2];   // [E,E]
    const float* Ua  = (const float*)d_in[3];   // [D,E]
    const float* Va  = (const float*)d_in[4];   // [E,1]

    float* c_out = (float*)d_out;                               // [B,Ty,E]
    float* e_out = (float*)d_out + (size_t)NB * TY * NE;        // [B,Ty,Tx]

    float* ZwT = (float*)d_ws;                                  // [B][E][Tx]
    float* Zu  = (float*)d_ws + (size_t)NB * NE * TX;           // [B][Ty][E]

    prep_kernel<<<256, dim3(64, 8), 0, stream>>>(enc, dec, Wa, Ua, ZwT, Zu);
    attn_kernel<<<512, dim3(64, 8), 0, stream>>>(enc, ZwT, Zu, Va, c_out, e_out);
}